// Round 4
// baseline (6504.231 us; speedup 1.0000x reference)
//
#include <hip/hip_runtime.h>
#include <hip/hip_bf16.h>
#include <stdint.h>

typedef unsigned short u16;
typedef unsigned int u32;
typedef __attribute__((ext_vector_type(8))) short short8;
typedef __attribute__((ext_vector_type(4))) float f32x4;
typedef __attribute__((ext_vector_type(4))) unsigned short u16x4;

__device__ __forceinline__ float bf2f(u16 h) {
    union { u32 u; float f; } c; c.u = ((u32)h) << 16; return c.f;
}
__device__ __forceinline__ u16 f2bf(float f) {
    union { float f; u32 u; } c; c.f = f;
    u32 u = c.u;
    return (u16)((u + 0x7fffu + ((u >> 16) & 1u)) >> 16);
}

// ---------------------------------------------------------------------------
__global__ void k_init(int* flags) { flags[threadIdx.x] = 0; }

// cvec[i] = sum_k W_y[i,k]*b_out[k];  biasE[i] = cvec[i] + b_in[i] + b_y[i]
__global__ void k_c(const float* __restrict__ Wy, const float* __restrict__ bout,
                    const float* __restrict__ bin, const float* __restrict__ by,
                    float* __restrict__ cvec, float* __restrict__ biasE) {
    int i = blockIdx.x * 64 + threadIdx.x;
    const float* wr = Wy + (size_t)i * 512;
    float s = 0.f;
    for (int k = 0; k < 512; ++k) s += wr[k] * bout[k];
    cvec[i] = s;
    biasE[i] = s + bin[i] + by[i];
}

// z0mc[b,i] = sum_k ll[b,k]*W_y[i,k] - cvec[i]
__global__ __launch_bounds__(512) void k_z0(const float* __restrict__ ll,
                                            const float* __restrict__ Wy,
                                            const float* __restrict__ cvec,
                                            float* __restrict__ z0mc) {
    __shared__ float lls[512];
    int b = blockIdx.x, i = threadIdx.x;
    lls[i] = ll[b * 512 + i];
    __syncthreads();
    const float* wr = Wy + (size_t)i * 512;
    float s = 0.f;
    for (int k = 0; k < 512; ++k) s += wr[k] * lls[k];
    z0mc[(size_t)b * 512 + i] = s - cvec[i];
}

// split fp32 [512*512] -> hi/lo bf16 planes
__global__ __launch_bounds__(256) void k_split(const float* __restrict__ in,
                                               u16* __restrict__ hi,
                                               u16* __restrict__ lo) {
    int i = blockIdx.x * 256 + threadIdx.x;
    float v = in[i];
    u16 h = f2bf(v);
    hi[i] = h;
    lo[i] = f2bf(v - bf2f(h));
}

// transpose+split fp32 512x512: out[j,k] = in[k,j] as hi/lo bf16 planes
__global__ __launch_bounds__(256) void k_tsplit(const float* __restrict__ in,
                                                u16* __restrict__ hi,
                                                u16* __restrict__ lo) {
    __shared__ float tile[32][33];
    int bx = blockIdx.x, by = blockIdx.y;
    int tx = threadIdx.x & 31, ty = threadIdx.x >> 5;  // 32 x 8
    for (int i = 0; i < 32; i += 8)
        tile[ty + i][tx] = in[(size_t)(by * 32 + ty + i) * 512 + bx * 32 + tx];
    __syncthreads();
    for (int i = 0; i < 32; i += 8) {
        float v = tile[tx][ty + i];
        size_t idx = (size_t)(bx * 32 + ty + i) * 512 + by * 32 + tx;
        u16 h = f2bf(v);
        hi[idx] = h;
        lo[idx] = f2bf(v - bf2f(h));
    }
}

// ---------------------------------------------------------------------------
// gemm3: C[row,col] = sum_k A[row,k]*B[col,k] (+bias), B as hi/lo bf16 planes.
// A fp32 (a_fp32=1: on-the-fly hi/lo split, 3 MFMA products) or bf16 (2).
// mode 0: out bf16 hi/lo planes (out_hi/out_lo), no bias.
// mode 1: out fp32 plane (out_f), bias fp32 added.
// ---------------------------------------------------------------------------
__global__ __launch_bounds__(256) void gemm3(
    const void* __restrict__ Aptr, int a_fp32,
    const u16* __restrict__ Bhi, const u16* __restrict__ Blo,
    u16* __restrict__ out_hi, u16* __restrict__ out_lo,
    float* __restrict__ out_f,
    const float* __restrict__ bias, int mode) {
    __shared__ u16 AsHi[128 * 32];
    __shared__ u16 AsLo[128 * 32];
    __shared__ u16 BsHi[128 * 32];
    __shared__ u16 BsLo[128 * 32];
    const int tid = threadIdx.x;
    const int lane = tid & 63;
    const int w = tid >> 6;
    const int wm = w & 1, wn = w >> 1;
    const int quad = lane >> 4, l15 = lane & 15;
    const int tx = blockIdx.x, tn = blockIdx.y;

    f32x4 acc[4][4];
    f32x4 zero4 = {0.f, 0.f, 0.f, 0.f};
#pragma unroll
    for (int i = 0; i < 4; ++i)
#pragma unroll
        for (int j = 0; j < 4; ++j) acc[i][j] = zero4;

    const float* Af = (const float*)Aptr;
    const u16* Ab = (const u16*)Aptr;
    const int s0 = tid, s1 = tid + 256;

    for (int kk = 0; kk < 16; ++kk) {
        const uint4* BgH = (const uint4*)(Bhi + (size_t)tn * 128 * 512 + kk * 32);
        const uint4* BgL = (const uint4*)(Blo + (size_t)tn * 128 * 512 + kk * 32);
        uint4 bh0 = BgH[(s0 >> 2) * 64 + (s0 & 3)];
        uint4 bh1 = BgH[(s1 >> 2) * 64 + (s1 & 3)];
        uint4 bl0 = BgL[(s0 >> 2) * 64 + (s0 & 3)];
        uint4 bl1 = BgL[(s1 >> 2) * 64 + (s1 & 3)];
        f32x4 av[4];
        uint4 ab0, ab1;
        if (a_fp32) {
            const float* Agf = Af + (size_t)tx * 128 * 512 + kk * 32;
#pragma unroll
            for (int p = 0; p < 4; ++p) {
                int f = tid + p * 256;
                av[p] = *(const f32x4*)(Agf + (f >> 3) * 512 + (f & 7) * 4);
            }
        } else {
            const uint4* Ag = (const uint4*)(Ab + (size_t)tx * 128 * 512 + kk * 32);
            ab0 = Ag[(s0 >> 2) * 64 + (s0 & 3)];
            ab1 = Ag[(s1 >> 2) * 64 + (s1 & 3)];
        }
        __syncthreads();
        ((uint4*)BsHi)[s0] = bh0; ((uint4*)BsHi)[s1] = bh1;
        ((uint4*)BsLo)[s0] = bl0; ((uint4*)BsLo)[s1] = bl1;
        if (a_fp32) {
#pragma unroll
            for (int p = 0; p < 4; ++p) {
                int f = tid + p * 256;
                u16x4 hi4, lo4;
#pragma unroll
                for (int j = 0; j < 4; ++j) {
                    float v = av[p][j];
                    u16 hh = f2bf(v);
                    hi4[j] = hh;
                    lo4[j] = f2bf(v - bf2f(hh));
                }
                int off = (f >> 3) * 32 + (f & 7) * 4;
                *(u16x4*)(AsHi + off) = hi4;
                *(u16x4*)(AsLo + off) = lo4;
            }
        } else {
            ((uint4*)AsHi)[s0] = ab0;
            ((uint4*)AsHi)[s1] = ab1;
        }
        __syncthreads();

        short8 afh[4], afl[4], bfh[4], bfl[4];
#pragma unroll
        for (int mi = 0; mi < 4; ++mi) {
            afh[mi] = *(const short8*)(AsHi + (wm * 64 + mi * 16 + l15) * 32 + quad * 8);
            if (a_fp32)
                afl[mi] = *(const short8*)(AsLo + (wm * 64 + mi * 16 + l15) * 32 + quad * 8);
        }
#pragma unroll
        for (int ni = 0; ni < 4; ++ni) {
            bfh[ni] = *(const short8*)(BsHi + (wn * 64 + ni * 16 + l15) * 32 + quad * 8);
            bfl[ni] = *(const short8*)(BsLo + (wn * 64 + ni * 16 + l15) * 32 + quad * 8);
        }
#pragma unroll
        for (int mi = 0; mi < 4; ++mi)
#pragma unroll
            for (int ni = 0; ni < 4; ++ni) {
                acc[mi][ni] = __builtin_amdgcn_mfma_f32_16x16x32_bf16(
                    afh[mi], bfh[ni], acc[mi][ni], 0, 0, 0);
                acc[mi][ni] = __builtin_amdgcn_mfma_f32_16x16x32_bf16(
                    afh[mi], bfl[ni], acc[mi][ni], 0, 0, 0);
                if (a_fp32)
                    acc[mi][ni] = __builtin_amdgcn_mfma_f32_16x16x32_bf16(
                        afl[mi], bfh[ni], acc[mi][ni], 0, 0, 0);
            }
    }

#pragma unroll
    for (int mi = 0; mi < 4; ++mi) {
#pragma unroll
        for (int ni = 0; ni < 4; ++ni) {
            int col = tn * 128 + wn * 64 + ni * 16 + l15;
            float bv = (mode == 1) ? bias[col] : 0.f;
#pragma unroll
            for (int r = 0; r < 4; ++r) {
                int row = tx * 128 + wm * 64 + mi * 16 + quad * 4 + r;
                float v = acc[mi][ni][r] + bv;
                size_t idx = (size_t)row * 512 + col;
                if (mode == 0) {
                    u16 hi = f2bf(v);
                    out_hi[idx] = hi;
                    out_lo[idx] = f2bf(v - bf2f(hi));
                } else {
                    out_f[idx] = v;
                }
            }
        }
    }
}

// ---------------------------------------------------------------------------
// Scan: 64 WGs = 4 batch-groups(g) x 16 h-slices(s). h_t = tanh(e_t + M h_{t-1}).
// M slice (32 rows x 512) in registers as MFMA B-frags (hi/lo), K split over
// 4 waves. h exchanged between WGs of a group via global h_ex (packed hi|lo
// bf16). e lives as fp32 in the h region of d_out and is overwritten in place
// by fp32 h (same thread, read-then-write).
// ---------------------------------------------------------------------------
__global__ __launch_bounds__(256) void k_scan(
    const u16* __restrict__ Mhi, const u16* __restrict__ Mlo,
    float* e_io,                   // [b*512+t][512] fp32: e in, h out
    const float* __restrict__ z0mc,
    u32* h_ex,                     // [2][4][16*512] packed (lo<<16)|hi
    int* flags)                    // [64]
{
    __shared__ float zpart[2 * 4 * 4 * 64];  // [nt][w][reg][lane]

    const int tid = threadIdx.x;
    const int lane = tid & 63, w = tid >> 6;
    const int quad = lane >> 4, l15 = lane & 15;
    const int g = blockIdx.x & 3, s = blockIdx.x >> 2;

    // register-resident M fragments: lane holds
    // M[s*32 + nt*16 + l15][w*128 + kap*32 + quad*8 + j]
    short8 mf[2][4][2];
#pragma unroll
    for (int nt = 0; nt < 2; ++nt)
#pragma unroll
        for (int kap = 0; kap < 4; ++kap) {
            size_t off = ((size_t)(s * 32 + nt * 16 + l15)) * 512 +
                         (w * 128 + kap * 32 + quad * 8);
            mf[nt][kap][0] = *(const short8*)(Mhi + off);
            mf[nt][kap][1] = *(const short8*)(Mlo + off);
        }

    const int erow = tid >> 4;       // 0..15
    const int ec0 = (tid & 15) * 2;  // 0..30
    const int bb = g * 16 + erow;

#pragma unroll 1
    for (int t = 0; t < 512; ++t) {
        if (t > 0) {
            const u32* ex = h_ex + (size_t)(((t - 1) & 1) * 4 + g) * 8192;
            f32x4 acc[2];
            f32x4 zero4 = {0.f, 0.f, 0.f, 0.f};
            acc[0] = zero4; acc[1] = zero4;
#pragma unroll
            for (int kap = 0; kap < 4; ++kap) {
                const u32* p = ex + l15 * 512 + w * 128 + kap * 32 + quad * 8;
                uint4 q0 = *(const uint4*)(p);
                uint4 q1 = *(const uint4*)(p + 4);
                u32 qs[8] = {q0.x, q0.y, q0.z, q0.w, q1.x, q1.y, q1.z, q1.w};
                short8 ahi, alo;
#pragma unroll
                for (int j = 0; j < 8; ++j) {
                    ahi[j] = (short)(qs[j] & 0xffffu);
                    alo[j] = (short)(qs[j] >> 16);
                }
#pragma unroll
                for (int nt = 0; nt < 2; ++nt) {
                    acc[nt] = __builtin_amdgcn_mfma_f32_16x16x32_bf16(
                        ahi, mf[nt][kap][0], acc[nt], 0, 0, 0);
                    acc[nt] = __builtin_amdgcn_mfma_f32_16x16x32_bf16(
                        alo, mf[nt][kap][0], acc[nt], 0, 0, 0);
                    acc[nt] = __builtin_amdgcn_mfma_f32_16x16x32_bf16(
                        ahi, mf[nt][kap][1], acc[nt], 0, 0, 0);
                }
            }
#pragma unroll
            for (int nt = 0; nt < 2; ++nt)
#pragma unroll
                for (int r = 0; r < 4; ++r)
                    zpart[((nt * 4 + w) * 4 + r) * 64 + lane] = acc[nt][r];
        }
        __syncthreads();  // B1: zpart ready

#pragma unroll
        for (int cc = 0; cc < 2; ++cc) {
            int col = ec0 + cc;
            int gcol = s * 32 + col;
            size_t idx = ((size_t)bb * 512 + t) * 512 + gcol;
            float ev = e_io[idx];  // e (fp32, pre-overwrite)
            float z;
            if (t == 0) {
                z = z0mc[(size_t)bb * 512 + gcol];
            } else {
                int nt = col >> 4;
                int lp = (erow >> 2) * 16 + (col & 15);
                int rg = erow & 3;
                z = zpart[((nt * 4 + 0) * 4 + rg) * 64 + lp] +
                    zpart[((nt * 4 + 1) * 4 + rg) * 64 + lp] +
                    zpart[((nt * 4 + 2) * 4 + rg) * 64 + lp] +
                    zpart[((nt * 4 + 3) * 4 + rg) * 64 + lp];
            }
            float hval = tanhf(z + ev);
            e_io[idx] = hval;  // overwrite e with h (fp32)
            u16 hi = f2bf(hval);
            u16 lo = f2bf(hval - bf2f(hi));
            h_ex[(size_t)((t & 1) * 4 + g) * 8192 + erow * 512 + gcol] =
                (((u32)lo) << 16) | (u32)hi;
        }
        __threadfence();  // publish h_ex stores device-wide
        __syncthreads();  // B2
        if (tid == 0)
            __hip_atomic_store(&flags[g * 16 + s], t + 1, __ATOMIC_RELEASE,
                               __HIP_MEMORY_SCOPE_AGENT);
        if (w == 0 && lane < 16) {
            while (__hip_atomic_load(&flags[g * 16 + lane], __ATOMIC_RELAXED,
                                     __HIP_MEMORY_SCOPE_AGENT) < t + 1)
                __builtin_amdgcn_s_sleep(2);
        }
        __syncthreads();  // B3
        __threadfence();  // acquire before next iteration's h_ex loads
    }
}

// ---------------------------------------------------------------------------
__global__ __launch_bounds__(512) void k_ylast(const float* __restrict__ yreg,
                                               float* __restrict__ ylast) {
    int b = blockIdx.x, o = threadIdx.x;
    ylast[(size_t)b * 512 + o] = yreg[((size_t)b * 512 + 511) * 512 + o];
}

// ---------------------------------------------------------------------------
extern "C" void kernel_launch(void* const* d_in, const int* in_sizes, int n_in,
                              void* d_out, int out_size, void* d_ws, size_t ws_size,
                              hipStream_t stream) {
    const float* emb  = (const float*)d_in[0];  // [64,512,512] fp32
    const float* ll   = (const float*)d_in[1];  // [64,512]
    const float* Win  = (const float*)d_in[2];  // [512,512]
    const float* bin  = (const float*)d_in[3];  // [512]
    const float* Wy   = (const float*)d_in[4];  // [512,512]
    const float* by   = (const float*)d_in[5];  // [512]
    const float* Wout = (const float*)d_in[6];  // [512,512]
    const float* bout = (const float*)d_in[7];  // [512]

    float* out = (float*)d_out;                 // fp32 outputs
    float* h_reg = out;                         // h: [b*512+t][512]
    float* y_reg = out + (size_t)16777216;      // y: [b*512+t][512]
    float* ylast_reg = out + (size_t)33554432;  // [64][512]

    // workspace (~2.5 MB)
    char* ws = (char*)d_ws;
    size_t off = 0;
    u16* buf1 = (u16*)(ws + off); off += (size_t)512 * 512 * 2;  // shared B hi
    u16* buf2 = (u16*)(ws + off); off += (size_t)512 * 512 * 2;  // shared B lo
    u16* Mhi  = (u16*)(ws + off); off += (size_t)512 * 512 * 2;
    u16* Mlo  = (u16*)(ws + off); off += (size_t)512 * 512 * 2;
    float* z0mc  = (float*)(ws + off); off += (size_t)64 * 512 * 4;
    float* cvec  = (float*)(ws + off); off += 512 * 4;
    float* biasE = (float*)(ws + off); off += 512 * 4;
    u32* h_ex = (u32*)(ws + off); off += (size_t)2 * 4 * 8192 * 4;
    int* flags = (int*)(ws + off); off += 64 * 4;

    k_init<<<1, 64, 0, stream>>>(flags);
    k_c<<<8, 64, 0, stream>>>(Wy, bout, bin, by, cvec, biasE);
    k_z0<<<64, 512, 0, stream>>>(ll, Wy, cvec, z0mc);
    // WoT hi/lo = transpose(W_out) split
    k_tsplit<<<dim3(16, 16), 256, 0, stream>>>(Wout, buf1, buf2);
    // M = W_y @ W_out -> bf16 hi/lo planes  (A = Wy fp32, B = WoT hi/lo)
    gemm3<<<dim3(4, 4), 256, 0, stream>>>(Wy, 1, buf1, buf2, Mhi, Mlo,
                                          nullptr, nullptr, 0);
    // Win hi/lo (reuse buffers)
    k_split<<<1024, 256, 0, stream>>>(Win, buf1, buf2);
    // e = emb @ W_in^T + (b_in + b_y + c) -> fp32 into h region
    gemm3<<<dim3(256, 4), 256, 0, stream>>>(emb, 1, buf1, buf2, nullptr, nullptr,
                                            h_reg, biasE, 1);
    // sequential scan: h region e -> h in place (fp32)
    k_scan<<<64, 256, 0, stream>>>(Mhi, Mlo, h_reg, z0mc, h_ex, flags);
    // Wout natural hi/lo (reuse buffers)
    k_split<<<1024, 256, 0, stream>>>(Wout, buf1, buf2);
    // y = h @ W_out^T + b_out (A = h fp32)
    gemm3<<<dim3(256, 4), 256, 0, stream>>>(h_reg, 1, buf1, buf2, nullptr, nullptr,
                                            y_reg, bout, 1);
    k_ylast<<<64, 512, 0, stream>>>(y_reg, ylast_reg);
}

// Round 5
// 2283.809 us; speedup vs baseline: 2.8480x; 2.8480x over previous
//
#include <hip/hip_runtime.h>
#include <hip/hip_bf16.h>
#include <stdint.h>

typedef unsigned short u16;
typedef unsigned int u32;
typedef unsigned long long u64;
typedef __attribute__((ext_vector_type(8))) short short8;
typedef __attribute__((ext_vector_type(4))) float f32x4;
typedef __attribute__((ext_vector_type(4))) unsigned short u16x4;

__device__ __forceinline__ float bf2f(u16 h) {
    union { u32 u; float f; } c; c.u = ((u32)h) << 16; return c.f;
}
__device__ __forceinline__ u16 f2bf(float f) {
    union { float f; u32 u; } c; c.f = f;
    u32 u = c.u;
    return (u16)((u + 0x7fffu + ((u >> 16) & 1u)) >> 16);
}

// ---------------------------------------------------------------------------
__global__ void k_init(int* flags) { flags[threadIdx.x] = 0; }

// cvec[i] = sum_k W_y[i,k]*b_out[k];  biasE[i] = cvec[i] + b_in[i] + b_y[i]
__global__ void k_c(const float* __restrict__ Wy, const float* __restrict__ bout,
                    const float* __restrict__ bin, const float* __restrict__ by,
                    float* __restrict__ cvec, float* __restrict__ biasE) {
    int i = blockIdx.x * 64 + threadIdx.x;
    const float* wr = Wy + (size_t)i * 512;
    float s = 0.f;
    for (int k = 0; k < 512; ++k) s += wr[k] * bout[k];
    cvec[i] = s;
    biasE[i] = s + bin[i] + by[i];
}

// z0mc[b,i] = sum_k ll[b,k]*W_y[i,k] - cvec[i]
__global__ __launch_bounds__(512) void k_z0(const float* __restrict__ ll,
                                            const float* __restrict__ Wy,
                                            const float* __restrict__ cvec,
                                            float* __restrict__ z0mc) {
    __shared__ float lls[512];
    int b = blockIdx.x, i = threadIdx.x;
    lls[i] = ll[b * 512 + i];
    __syncthreads();
    const float* wr = Wy + (size_t)i * 512;
    float s = 0.f;
    for (int k = 0; k < 512; ++k) s += wr[k] * lls[k];
    z0mc[(size_t)b * 512 + i] = s - cvec[i];
}

// split fp32 [512*512] -> hi/lo bf16 planes
__global__ __launch_bounds__(256) void k_split(const float* __restrict__ in,
                                               u16* __restrict__ hi,
                                               u16* __restrict__ lo) {
    int i = blockIdx.x * 256 + threadIdx.x;
    float v = in[i];
    u16 h = f2bf(v);
    hi[i] = h;
    lo[i] = f2bf(v - bf2f(h));
}

// transpose+split fp32 512x512: out[j,k] = in[k,j] as hi/lo bf16 planes
__global__ __launch_bounds__(256) void k_tsplit(const float* __restrict__ in,
                                                u16* __restrict__ hi,
                                                u16* __restrict__ lo) {
    __shared__ float tile[32][33];
    int bx = blockIdx.x, by = blockIdx.y;
    int tx = threadIdx.x & 31, ty = threadIdx.x >> 5;  // 32 x 8
    for (int i = 0; i < 32; i += 8)
        tile[ty + i][tx] = in[(size_t)(by * 32 + ty + i) * 512 + bx * 32 + tx];
    __syncthreads();
    for (int i = 0; i < 32; i += 8) {
        float v = tile[tx][ty + i];
        size_t idx = (size_t)(bx * 32 + ty + i) * 512 + by * 32 + tx;
        u16 h = f2bf(v);
        hi[idx] = h;
        lo[idx] = f2bf(v - bf2f(h));
    }
}

// ---------------------------------------------------------------------------
// gemm3: C[row,col] = sum_k A[row,k]*B[col,k] (+bias), B as hi/lo bf16 planes.
// A fp32 (a_fp32=1: on-the-fly hi/lo split, 3 MFMA products) or bf16 (2).
// mode 0: out bf16 hi/lo planes (out_hi/out_lo), no bias.
// mode 1: out fp32 plane (out_f), bias fp32 added.
// ---------------------------------------------------------------------------
__global__ __launch_bounds__(256) void gemm3(
    const void* __restrict__ Aptr, int a_fp32,
    const u16* __restrict__ Bhi, const u16* __restrict__ Blo,
    u16* __restrict__ out_hi, u16* __restrict__ out_lo,
    float* __restrict__ out_f,
    const float* __restrict__ bias, int mode) {
    __shared__ u16 AsHi[128 * 32];
    __shared__ u16 AsLo[128 * 32];
    __shared__ u16 BsHi[128 * 32];
    __shared__ u16 BsLo[128 * 32];
    const int tid = threadIdx.x;
    const int lane = tid & 63;
    const int w = tid >> 6;
    const int wm = w & 1, wn = w >> 1;
    const int quad = lane >> 4, l15 = lane & 15;
    const int tx = blockIdx.x, tn = blockIdx.y;

    f32x4 acc[4][4];
    f32x4 zero4 = {0.f, 0.f, 0.f, 0.f};
#pragma unroll
    for (int i = 0; i < 4; ++i)
#pragma unroll
        for (int j = 0; j < 4; ++j) acc[i][j] = zero4;

    const float* Af = (const float*)Aptr;
    const u16* Ab = (const u16*)Aptr;
    const int s0 = tid, s1 = tid + 256;

    for (int kk = 0; kk < 16; ++kk) {
        const uint4* BgH = (const uint4*)(Bhi + (size_t)tn * 128 * 512 + kk * 32);
        const uint4* BgL = (const uint4*)(Blo + (size_t)tn * 128 * 512 + kk * 32);
        uint4 bh0 = BgH[(s0 >> 2) * 64 + (s0 & 3)];
        uint4 bh1 = BgH[(s1 >> 2) * 64 + (s1 & 3)];
        uint4 bl0 = BgL[(s0 >> 2) * 64 + (s0 & 3)];
        uint4 bl1 = BgL[(s1 >> 2) * 64 + (s1 & 3)];
        f32x4 av[4];
        uint4 ab0, ab1;
        if (a_fp32) {
            const float* Agf = Af + (size_t)tx * 128 * 512 + kk * 32;
#pragma unroll
            for (int p = 0; p < 4; ++p) {
                int f = tid + p * 256;
                av[p] = *(const f32x4*)(Agf + (f >> 3) * 512 + (f & 7) * 4);
            }
        } else {
            const uint4* Ag = (const uint4*)(Ab + (size_t)tx * 128 * 512 + kk * 32);
            ab0 = Ag[(s0 >> 2) * 64 + (s0 & 3)];
            ab1 = Ag[(s1 >> 2) * 64 + (s1 & 3)];
        }
        __syncthreads();
        ((uint4*)BsHi)[s0] = bh0; ((uint4*)BsHi)[s1] = bh1;
        ((uint4*)BsLo)[s0] = bl0; ((uint4*)BsLo)[s1] = bl1;
        if (a_fp32) {
#pragma unroll
            for (int p = 0; p < 4; ++p) {
                int f = tid + p * 256;
                u16x4 hi4, lo4;
#pragma unroll
                for (int j = 0; j < 4; ++j) {
                    float v = av[p][j];
                    u16 hh = f2bf(v);
                    hi4[j] = hh;
                    lo4[j] = f2bf(v - bf2f(hh));
                }
                int off = (f >> 3) * 32 + (f & 7) * 4;
                *(u16x4*)(AsHi + off) = hi4;
                *(u16x4*)(AsLo + off) = lo4;
            }
        } else {
            ((uint4*)AsHi)[s0] = ab0;
            ((uint4*)AsHi)[s1] = ab1;
        }
        __syncthreads();

        short8 afh[4], afl[4], bfh[4], bfl[4];
#pragma unroll
        for (int mi = 0; mi < 4; ++mi) {
            afh[mi] = *(const short8*)(AsHi + (wm * 64 + mi * 16 + l15) * 32 + quad * 8);
            if (a_fp32)
                afl[mi] = *(const short8*)(AsLo + (wm * 64 + mi * 16 + l15) * 32 + quad * 8);
        }
#pragma unroll
        for (int ni = 0; ni < 4; ++ni) {
            bfh[ni] = *(const short8*)(BsHi + (wn * 64 + ni * 16 + l15) * 32 + quad * 8);
            bfl[ni] = *(const short8*)(BsLo + (wn * 64 + ni * 16 + l15) * 32 + quad * 8);
        }
#pragma unroll
        for (int mi = 0; mi < 4; ++mi)
#pragma unroll
            for (int ni = 0; ni < 4; ++ni) {
                acc[mi][ni] = __builtin_amdgcn_mfma_f32_16x16x32_bf16(
                    afh[mi], bfh[ni], acc[mi][ni], 0, 0, 0);
                acc[mi][ni] = __builtin_amdgcn_mfma_f32_16x16x32_bf16(
                    afh[mi], bfl[ni], acc[mi][ni], 0, 0, 0);
                if (a_fp32)
                    acc[mi][ni] = __builtin_amdgcn_mfma_f32_16x16x32_bf16(
                        afl[mi], bfh[ni], acc[mi][ni], 0, 0, 0);
            }
    }

#pragma unroll
    for (int mi = 0; mi < 4; ++mi) {
#pragma unroll
        for (int ni = 0; ni < 4; ++ni) {
            int col = tn * 128 + wn * 64 + ni * 16 + l15;
            float bv = (mode == 1) ? bias[col] : 0.f;
#pragma unroll
            for (int r = 0; r < 4; ++r) {
                int row = tx * 128 + wm * 64 + mi * 16 + quad * 4 + r;
                float v = acc[mi][ni][r] + bv;
                size_t idx = (size_t)row * 512 + col;
                if (mode == 0) {
                    u16 hi = f2bf(v);
                    out_hi[idx] = hi;
                    out_lo[idx] = f2bf(v - bf2f(hi));
                } else {
                    out_f[idx] = v;
                }
            }
        }
    }
}

// ---------------------------------------------------------------------------
// Scan: 64 WGs = 4 batch-groups(g) x 16 h-slices(s). h_t = tanh(e_t + M h_{t-1}).
// M slice in registers (launch_bounds(256,1) to prevent spill). Cross-WG h
// exchange via AGENT-scope relaxed atomics (sc1: bypass non-coherent L2) —
// NO __threadfence (no buffer_wbl2 L2 flush in the loop). Ordering comes from
// __syncthreads' implicit vmcnt(0) drain before s_barrier: at B2-exit all
// write-through h_ex stores are globally visible, so the relaxed flag store
// publishing t+1 is correctly ordered.
// ---------------------------------------------------------------------------
__global__ __launch_bounds__(256, 1) void k_scan(
    const u16* __restrict__ Mhi, const u16* __restrict__ Mlo,
    float* e_io,                   // [b*512+t][512] fp32: e in, h out
    const float* __restrict__ z0mc,
    u32* h_ex,                     // [2][4][16*512] packed (lo<<16)|hi
    int* flags)                    // [64]
{
    __shared__ float zpart[2 * 4 * 4 * 64];  // [nt][w][reg][lane]

    const int tid = threadIdx.x;
    const int lane = tid & 63, w = tid >> 6;
    const int quad = lane >> 4, l15 = lane & 15;
    const int g = blockIdx.x & 3, s = blockIdx.x >> 2;

    // register-resident M fragments: lane holds
    // M[s*32 + nt*16 + l15][w*128 + kap*32 + quad*8 + j]
    short8 mf[2][4][2];
#pragma unroll
    for (int nt = 0; nt < 2; ++nt)
#pragma unroll
        for (int kap = 0; kap < 4; ++kap) {
            size_t off = ((size_t)(s * 32 + nt * 16 + l15)) * 512 +
                         (w * 128 + kap * 32 + quad * 8);
            mf[nt][kap][0] = *(const short8*)(Mhi + off);
            mf[nt][kap][1] = *(const short8*)(Mlo + off);
        }

    const int erow = tid >> 4;       // 0..15
    const int ec0 = (tid & 15) * 2;  // 0..30
    const int bb = g * 16 + erow;

#pragma unroll 1
    for (int t = 0; t < 512; ++t) {
        if (t > 0) {
            const u64* ex = (const u64*)(h_ex +
                (size_t)(((t - 1) & 1) * 4 + g) * 8192);
            f32x4 acc[2];
            f32x4 zero4 = {0.f, 0.f, 0.f, 0.f};
            acc[0] = zero4; acc[1] = zero4;
#pragma unroll
            for (int kap = 0; kap < 4; ++kap) {
                const u64* p = ex + (l15 * 512 + w * 128 + kap * 32 + quad * 8) / 2;
                u64 d0 = __hip_atomic_load(p + 0, __ATOMIC_RELAXED,
                                           __HIP_MEMORY_SCOPE_AGENT);
                u64 d1 = __hip_atomic_load(p + 1, __ATOMIC_RELAXED,
                                           __HIP_MEMORY_SCOPE_AGENT);
                u64 d2 = __hip_atomic_load(p + 2, __ATOMIC_RELAXED,
                                           __HIP_MEMORY_SCOPE_AGENT);
                u64 d3 = __hip_atomic_load(p + 3, __ATOMIC_RELAXED,
                                           __HIP_MEMORY_SCOPE_AGENT);
                u32 qs[8] = {(u32)d0, (u32)(d0 >> 32), (u32)d1, (u32)(d1 >> 32),
                             (u32)d2, (u32)(d2 >> 32), (u32)d3, (u32)(d3 >> 32)};
                short8 ahi, alo;
#pragma unroll
                for (int j = 0; j < 8; ++j) {
                    ahi[j] = (short)(qs[j] & 0xffffu);
                    alo[j] = (short)(qs[j] >> 16);
                }
#pragma unroll
                for (int nt = 0; nt < 2; ++nt) {
                    acc[nt] = __builtin_amdgcn_mfma_f32_16x16x32_bf16(
                        ahi, mf[nt][kap][0], acc[nt], 0, 0, 0);
                    acc[nt] = __builtin_amdgcn_mfma_f32_16x16x32_bf16(
                        alo, mf[nt][kap][0], acc[nt], 0, 0, 0);
                    acc[nt] = __builtin_amdgcn_mfma_f32_16x16x32_bf16(
                        ahi, mf[nt][kap][1], acc[nt], 0, 0, 0);
                }
            }
#pragma unroll
            for (int nt = 0; nt < 2; ++nt)
#pragma unroll
                for (int r = 0; r < 4; ++r)
                    zpart[((nt * 4 + w) * 4 + r) * 64 + lane] = acc[nt][r];
        }
        __syncthreads();  // B1: zpart ready

        {
            float hv[2];
#pragma unroll
            for (int cc = 0; cc < 2; ++cc) {
                int col = ec0 + cc;
                int gcol = s * 32 + col;
                size_t idx = ((size_t)bb * 512 + t) * 512 + gcol;
                float ev = e_io[idx];  // e (fp32, pre-overwrite)
                float z;
                if (t == 0) {
                    z = z0mc[(size_t)bb * 512 + gcol];
                } else {
                    int nt = col >> 4;
                    int lp = (erow >> 2) * 16 + (col & 15);
                    int rg = erow & 3;
                    z = zpart[((nt * 4 + 0) * 4 + rg) * 64 + lp] +
                        zpart[((nt * 4 + 1) * 4 + rg) * 64 + lp] +
                        zpart[((nt * 4 + 2) * 4 + rg) * 64 + lp] +
                        zpart[((nt * 4 + 3) * 4 + rg) * 64 + lp];
                }
                float hval = tanhf(z + ev);
                e_io[idx] = hval;  // overwrite e with h (fp32, plain store)
                hv[cc] = hval;
            }
            // pack 2 cols -> one u64, write-through (sc1) store
            u32 pk[2];
#pragma unroll
            for (int cc = 0; cc < 2; ++cc) {
                u16 hi = f2bf(hv[cc]);
                u16 lo = f2bf(hv[cc] - bf2f(hi));
                pk[cc] = (((u32)lo) << 16) | (u32)hi;
            }
            u64 val = ((u64)pk[1] << 32) | pk[0];
            u64* dst = (u64*)(h_ex + (size_t)((t & 1) * 4 + g) * 8192 +
                              erow * 512 + s * 32 + ec0);
            __hip_atomic_store(dst, val, __ATOMIC_RELAXED,
                               __HIP_MEMORY_SCOPE_AGENT);
        }
        __syncthreads();  // B2: implicit vmcnt(0) drain -> h_ex stores visible
        __asm__ volatile("" ::: "memory");
        if (tid == 0)
            __hip_atomic_store(&flags[g * 16 + s], t + 1, __ATOMIC_RELAXED,
                               __HIP_MEMORY_SCOPE_AGENT);
        if (w == 0 && lane < 16) {
            while (__hip_atomic_load(&flags[g * 16 + lane], __ATOMIC_RELAXED,
                                     __HIP_MEMORY_SCOPE_AGENT) < t + 1)
                __builtin_amdgcn_s_sleep(1);
        }
        __syncthreads();  // B3: all slices of group g published
        __asm__ volatile("" ::: "memory");
    }
}

// ---------------------------------------------------------------------------
__global__ __launch_bounds__(512) void k_ylast(const float* __restrict__ yreg,
                                               float* __restrict__ ylast) {
    int b = blockIdx.x, o = threadIdx.x;
    ylast[(size_t)b * 512 + o] = yreg[((size_t)b * 512 + 511) * 512 + o];
}

// ---------------------------------------------------------------------------
extern "C" void kernel_launch(void* const* d_in, const int* in_sizes, int n_in,
                              void* d_out, int out_size, void* d_ws, size_t ws_size,
                              hipStream_t stream) {
    const float* emb  = (const float*)d_in[0];  // [64,512,512] fp32
    const float* ll   = (const float*)d_in[1];  // [64,512]
    const float* Win  = (const float*)d_in[2];  // [512,512]
    const float* bin  = (const float*)d_in[3];  // [512]
    const float* Wy   = (const float*)d_in[4];  // [512,512]
    const float* by   = (const float*)d_in[5];  // [512]
    const float* Wout = (const float*)d_in[6];  // [512,512]
    const float* bout = (const float*)d_in[7];  // [512]

    float* out = (float*)d_out;                 // fp32 outputs
    float* h_reg = out;                         // h: [b*512+t][512]
    float* y_reg = out + (size_t)16777216;      // y: [b*512+t][512]
    float* ylast_reg = out + (size_t)33554432;  // [64][512]

    // workspace (~2.5 MB)
    char* ws = (char*)d_ws;
    size_t off = 0;
    u16* buf1 = (u16*)(ws + off); off += (size_t)512 * 512 * 2;  // shared B hi
    u16* buf2 = (u16*)(ws + off); off += (size_t)512 * 512 * 2;  // shared B lo
    u16* Mhi  = (u16*)(ws + off); off += (size_t)512 * 512 * 2;
    u16* Mlo  = (u16*)(ws + off); off += (size_t)512 * 512 * 2;
    float* z0mc  = (float*)(ws + off); off += (size_t)64 * 512 * 4;
    float* cvec  = (float*)(ws + off); off += 512 * 4;
    float* biasE = (float*)(ws + off); off += 512 * 4;
    u32* h_ex = (u32*)(ws + off); off += (size_t)2 * 4 * 8192 * 4;
    int* flags = (int*)(ws + off); off += 64 * 4;

    k_init<<<1, 64, 0, stream>>>(flags);
    k_c<<<8, 64, 0, stream>>>(Wy, bout, bin, by, cvec, biasE);
    k_z0<<<64, 512, 0, stream>>>(ll, Wy, cvec, z0mc);
    // WoT hi/lo = transpose(W_out) split
    k_tsplit<<<dim3(16, 16), 256, 0, stream>>>(Wout, buf1, buf2);
    // M = W_y @ W_out -> bf16 hi/lo planes  (A = Wy fp32, B = WoT hi/lo)
    gemm3<<<dim3(4, 4), 256, 0, stream>>>(Wy, 1, buf1, buf2, Mhi, Mlo,
                                          nullptr, nullptr, 0);
    // Win hi/lo (reuse buffers)
    k_split<<<1024, 256, 0, stream>>>(Win, buf1, buf2);
    // e = emb @ W_in^T + (b_in + b_y + c) -> fp32 into h region
    gemm3<<<dim3(256, 4), 256, 0, stream>>>(emb, 1, buf1, buf2, nullptr, nullptr,
                                            h_reg, biasE, 1);
    // sequential scan: h region e -> h in place (fp32)
    k_scan<<<64, 256, 0, stream>>>(Mhi, Mlo, h_reg, z0mc, h_ex, flags);
    // Wout natural hi/lo (reuse buffers)
    k_split<<<1024, 256, 0, stream>>>(Wout, buf1, buf2);
    // y = h @ W_out^T + b_out (A = h fp32)
    gemm3<<<dim3(256, 4), 256, 0, stream>>>(h_reg, 1, buf1, buf2, nullptr, nullptr,
                                            y_reg, bout, 1);
    k_ylast<<<64, 512, 0, stream>>>(y_reg, ylast_reg);
}